// Round 7
// baseline (189.247 us; speedup 1.0000x reference)
//
#include <hip/hip_runtime.h>
#include <hip/hip_bf16.h>
#include <math.h>

#define Bn 8
#define Tn 2048
#define Cn 384
#define Hn 64
#define SCALE2 0.07362241f            // 384^-0.5 * log2(e); pre-folded into Wq
#define NBLK 512                      // attn grid: 2 blocks/CU exactly

using bf16x8 = __attribute__((ext_vector_type(8))) short;  // 8 bf16 = 4 VGPRs
using f32x4  = __attribute__((ext_vector_type(4))) float;
using u32x4  = __attribute__((ext_vector_type(4))) unsigned;

#define MFMA(a, b, c) __builtin_amdgcn_mfma_f32_16x16x32_bf16((a), (b), (c), 0, 0, 0)

static __device__ __forceinline__ short f2bf(float f) {  // RNE fp32->bf16
  unsigned u = __float_as_uint(f);
  u += 0x7fffu + ((u >> 16) & 1u);
  return (short)(u >> 16);
}
static __device__ __forceinline__ float fexp2(float x) {  // v_exp_f32 (base-2)
#if __has_builtin(__builtin_amdgcn_exp2f)
  return __builtin_amdgcn_exp2f(x);
#else
  return exp2f(x);
#endif
}
static __device__ __forceinline__ float frcp(float x) {   // v_rcp_f32 (~1ulp)
#if __has_builtin(__builtin_amdgcn_rcpf)
  return __builtin_amdgcn_rcpf(x);
#else
  return 1.0f / x;
#endif
}
static __device__ __forceinline__ unsigned pack2(float lo, float hi) {
  return (unsigned)(unsigned short)f2bf(lo) | ((unsigned)(unsigned short)f2bf(hi) << 16);
}
// Typed (TBAA-safe) LDS 16B gather: 4 x u32 loads, compiler merges to b128.
static __device__ __forceinline__ bf16x8 ldp(const unsigned* p) {
  u32x4 t; t[0] = p[0]; t[1] = p[1]; t[2] = p[2]; t[3] = p[3];
  return __builtin_bit_cast(bf16x8, t);
}
// Software grid barrier (graph-capture-safe; co-residency by construction:
// VGPR<=128 (waves_per_eu(4)) + LDS 58KB -> exactly 2 blocks/CU x 256 CU = 512).
static __device__ __forceinline__ void grid_barrier(unsigned* cnt) {
  __syncthreads();
  if (threadIdx.x == 0) {
    __threadfence();                          // release my Lsum atomics
    atomicAdd(cnt, 1u);                       // device-scope arrive
    while (__hip_atomic_load(cnt, __ATOMIC_ACQUIRE, __HIP_MEMORY_SCOPE_AGENT)
           < (unsigned)NBLK)
      __builtin_amdgcn_s_sleep(8);
  }
  __syncthreads();
}

// ---------------- K0: W -> WbT (192x384) bf16 (Wq pre-scaled) + zero Lsum ---
__global__ __launch_bounds__(256) void wconv_kernel(
    const float* __restrict__ Wq, const float* __restrict__ Wk,
    const float* __restrict__ Wv, short* __restrict__ WbT,
    float* __restrict__ Lsum, unsigned* __restrict__ bar) {
  int idx = blockIdx.x * 256 + threadIdx.x;  // n*384 + k, 73728 total
  if (idx < Bn * Tn) Lsum[idx] = 0.f;        // 16384 floats, pre-attn
  if (idx == 0) *bar = 0u;                   // grid-barrier counter
  int n = idx / 384, k = idx - n * 384;
  const float* W = (n < 64) ? Wq : (n < 128) ? Wk : Wv;
  float wv = W[k * 64 + (n & 63)];
  if (n < 64) wv *= SCALE2;                  // fold score scale into q
  WbT[idx] = f2bf(wv);
}

// ---------------- K1: proj GEMM, 16-row tiles (1024 blocks, 4/CU) -----------
__global__ __launch_bounds__(256) void proj_kernel(
    const float* __restrict__ x, const short* __restrict__ WbT,
    short* __restrict__ qb, short* __restrict__ kb, short* __restrict__ vT) {
  __shared__ short xs[16][392];    // stride 392: banks 2-way (free)
  __shared__ short vtile[64][20];  // v-tile transpose bounce
  const int tid = threadIdx.x;
  const int t0 = blockIdx.x * 16;  // global row (b*2048 + t)
  const float* xb = x + (size_t)t0 * Cn;
  #pragma unroll
  for (int i = 0; i < 6; ++i) {
    int j = tid + i * 256;  // float4 index, 1536 total
    int row = j / 96, colv = (j - row * 96) * 4;
    float4 v = *(const float4*)(xb + row * Cn + colv);
    short4 s4; s4.x = f2bf(v.x); s4.y = f2bf(v.y); s4.z = f2bf(v.z); s4.w = f2bf(v.w);
    *(short4*)(&xs[row][colv]) = s4;
  }
  __syncthreads();
  const int w = tid >> 6, l15 = tid & 15, quad = (tid & 63) >> 4;
  f32x4 acc[3] = {};
  for (int ks = 0; ks < 12; ++ks) {
    bf16x8 a = *(const bf16x8*)(&xs[l15][ks * 32 + quad * 8]);
    #pragma unroll
    for (int cf = 0; cf < 3; ++cf) {
      bf16x8 bfr = *(const bf16x8*)(WbT + (size_t)(48 * w + 16 * cf + l15) * Cn + ks * 32 + quad * 8);
      acc[cf] = MFMA(a, bfr, acc[cf]);
    }
  }
  #pragma unroll
  for (int cf = 0; cf < 3; ++cf) {
    int cbase = 48 * w + 16 * cf, c = cbase + l15;
    #pragma unroll
    for (int r = 0; r < 4; ++r) {
      int row = t0 + quad * 4 + r;
      short val = f2bf(acc[cf][r]);
      if (cbase < 64)       qb[(size_t)row * Hn + c] = val;
      else if (cbase < 128) kb[(size_t)row * Hn + (c - 64)] = val;
      else                  vtile[c - 128][quad * 4 + r] = val;
    }
  }
  __syncthreads();
  const int b = t0 >> 11, t0l = t0 & 2047;
  int h = tid >> 2, tseg = (tid & 3) * 4;
  *(short4*)(vT + ((size_t)(b * Hn + h)) * Tn + t0l + tseg) =
      *(const short4*)(&vtile[h][tseg]);
}

// ---------------- K2: FUSED attn: QK^T+exp ONCE, E in registers -------------
// 512 blocks x 512 thr (8 waves). amdgpu_waves_per_eu(4) -> VGPR cap 128
// (r6's launch_bounds(512,4) gave cap 64 -> Ereg spilled to scratch -> 100us).
// LDS 58KB -> exactly 2 blocks/CU; 512 co-resident -> barrier safe.
// Block = (b = bid&7, pair j, quarter): 16 rows of tile j + 16 rows of tile
// 31-j -> 33 chunk-items/block; waves 0-6 own 4 items, wave 7 owns 5.
// Items 0-3 keep packed E in Ereg[4][8] (32 VGPR); wave 7's 5th item goes to
// the eextra LDS buffer (wroff layout) instead of registers.
// Phase 1 per item: 8 MFMA S^T=K.Q' (D[s][t], lane&15=t), mask+exp2, pack,
//   column sums via width-16 shfl_xor butterfly -> LDS accumulate.
// Flush Lsum (coalesced atomics), software grid barrier, rcpL -> LDS.
// Phase 2 (two strip-passes): unpack E, *rcpL, repack, per-wave XOR-swizzled
//   LDS transpose (typed u32, no barriers), 8 PV MFMA vs vT; cross-wave
//   reduce via red[4][32][64]; coalesced float4 stores.
__global__ __launch_bounds__(512)
__attribute__((amdgpu_waves_per_eu(4)))
void attn_kernel(
    const short* __restrict__ qb, const short* __restrict__ kb,
    const short* __restrict__ vT, float* __restrict__ Lsum,
    unsigned* __restrict__ bar, float* __restrict__ out) {
  __shared__ alignas(16) float lsum_lds[2048];   // col sums, then rcpL (8KB)
  __shared__ alignas(16) unsigned plds[8][512];  // per-wave 2KB P tile (16KB)
  __shared__ alignas(16) float red[4][32][64];   // cross-wave reduce (32KB)
  __shared__ alignas(16) unsigned eextra[512];   // wave7 5th-item E (2KB)

  const int bid = blockIdx.x;
  const int b = bid & 7;                   // XCD-locked batch
  const int r_ = bid >> 3;                 // 0..63
  const int j = r_ >> 2;                   // pair 0..15
  const int quarter = r_ & 3;
  const int tA = j, tB = 31 - j;           // light tile, heavy tile
  const int tid = threadIdx.x;
  const int w = tid >> 6, l15 = tid & 15, quad = (tid & 63) >> 4;
  const int lo = (w * 33) >> 3, hi = ((w + 1) * 33) >> 3;  // 4 (w<7) or 5 (w=7)
  const int tb0 = (tA << 6) + (quarter << 4);
  const int tb1 = (tB << 6) + (quarter << 4);
  const size_t QKbase = (size_t)b * Tn * Hn;
  const size_t Vbase  = (size_t)b * Hn * Tn;

  for (int s = tid; s < 2048; s += 512) lsum_lds[s] = 0.f;
  __syncthreads();

  // XOR swizzle: byte ^= (l15&7)<<4 breaks the 128B-row same-bank pattern.
  const int swz = (l15 & 7) << 4;
  int wroff[8];                            // u32 offsets: s = 16nf+4q+{2p,2p+1}
  #pragma unroll
  for (int nf = 0; nf < 4; ++nf)
    #pragma unroll
    for (int p = 0; p < 2; ++p)
      wroff[2 * nf + p] = (l15 * 128 + ((nf * 32 + quad * 8 + p * 4) ^ swz)) >> 2;
  const int rd0 = (l15 * 128 + ((quad * 16) ^ swz)) >> 2;        // s = 8q..8q+7
  const int rd1 = (l15 * 128 + ((64 + quad * 16) ^ swz)) >> 2;   // s = 32+8q..+7

  auto chOf = [&](int g) { return (g > tA) ? (g - tA - 1) : g; };

  bf16x8 kf[8], vf[8];
  auto loadK = [&](int ch) {               // A[m=s][k=h] frags for S^T
    const int s0 = ch << 6;
    #pragma unroll
    for (int nf = 0; nf < 4; ++nf) {
      const size_t kr = QKbase + (size_t)(s0 + 16 * nf + l15) * Hn;
      kf[2 * nf]     = *(const bf16x8*)(kb + kr + quad * 8);
      kf[2 * nf + 1] = *(const bf16x8*)(kb + kr + 32 + quad * 8);
    }
  };
  auto loadV = [&](int ch) {               // B[n=h][k=s] frags for PV
    const int s0 = ch << 6;
    #pragma unroll
    for (int nf = 0; nf < 4; ++nf) {
      const size_t vr = Vbase + (size_t)(16 * nf + l15) * Tn + s0;
      vf[2 * nf]     = *(const bf16x8*)(vT + vr + quad * 8);
      vf[2 * nf + 1] = *(const bf16x8*)(vT + vr + 32 + quad * 8);
    }
  };

  // ---------------- phase 1: scores + exp + col-sums, E kept in regs --------
  unsigned Ereg[4][8];                     // statically indexed (unrolled i)
  loadK(chOf(lo));
  #pragma unroll
  for (int i = 0; i < 5; ++i) {
    const int g = lo + i;
    if (g < hi) {
      const int ch = chOf(g);
      const int tbase = (g > tA) ? tb1 : tb0;
      const bool diag = (ch == ((g > tA) ? tB : tA));
      const size_t qrow = QKbase + (size_t)(tbase + l15) * Hn;
      const bf16x8 qf0 = *(const bf16x8*)(qb + qrow + quad * 8);
      const bf16x8 qf1 = *(const bf16x8*)(qb + qrow + 32 + quad * 8);
      f32x4 sc[4] = {};                    // D[s][t]: lane&15 = t
      __builtin_amdgcn_s_setprio(1);
      #pragma unroll
      for (int nf = 0; nf < 4; ++nf) {
        sc[nf] = MFMA(kf[2 * nf], qf0, sc[nf]);
        sc[nf] = MFMA(kf[2 * nf + 1], qf1, sc[nf]);
      }
      __builtin_amdgcn_s_setprio(0);
      if (g + 1 < hi) loadK(chOf(g + 1));  // in flight under exp/butterfly
      const int tg = tbase + l15;
      #pragma unroll
      for (int nf = 0; nf < 4; ++nf) {
        f32x4 ev;
        if (diag) {
          #pragma unroll
          for (int r = 0; r < 4; ++r) {
            const int s = (ch << 6) + 16 * nf + 4 * quad + r;
            ev[r] = fexp2((tg < s) ? -INFINITY : sc[nf][r]);
          }
        } else {
          #pragma unroll
          for (int r = 0; r < 4; ++r) ev[r] = fexp2(sc[nf][r]);
        }
        if (i < 4) {
          Ereg[i][2 * nf]     = pack2(ev[0], ev[1]);
          Ereg[i][2 * nf + 1] = pack2(ev[2], ev[3]);
        } else {                           // only wave 7 reaches i==4
          eextra[wroff[2 * nf]]     = pack2(ev[0], ev[1]);
          eextra[wroff[2 * nf + 1]] = pack2(ev[2], ev[3]);
        }
        #pragma unroll
        for (int m = 1; m < 16; m <<= 1)   // sum over t (lane&15) per column
          #pragma unroll
          for (int r = 0; r < 4; ++r)
            ev[r] += __shfl_xor(ev[r], m, 16);
        if (l15 == 0) {
          #pragma unroll
          for (int r = 0; r < 4; ++r)
            atomicAdd(&lsum_lds[(ch << 6) + 16 * nf + 4 * quad + r], ev[r]);
        }
      }
    }
  }
  __syncthreads();
  for (int s = tid; s < 2048; s += 512)
    atomicAdd(&Lsum[b * Tn + s], lsum_lds[s]);   // coalesced flush
  grid_barrier(bar);
  for (int s = tid; s < 2048; s += 512)          // agent-scope load: coherent
    lsum_lds[s] = frcp(__hip_atomic_load(&Lsum[b * Tn + s],
                                         __ATOMIC_RELAXED,
                                         __HIP_MEMORY_SCOPE_AGENT));
  __syncthreads();

  // ---------------- phase 2: P = E*rcpL, transpose, PV, reduce, store -------
  f32x4 acc[4];
  auto pvpass = [&](bool stripB) {
    #pragma unroll
    for (int nf = 0; nf < 4; ++nf) acc[nf] = f32x4{0.f, 0.f, 0.f, 0.f};
    const int g0 = stripB ? ((lo > tA + 1) ? lo : tA + 1) : lo;
    const int g1 = stripB ? hi : ((hi < tA + 1) ? hi : tA + 1);
    if (g0 < g1) loadV(chOf(g0));
    #pragma unroll
    for (int i = 0; i < 5; ++i) {
      const int g = lo + i;
      if (g >= g0 && g < g1) {
        const int ch = chOf(g);
        #pragma unroll
        for (int nf = 0; nf < 4; ++nf) {
          float4 rl4 = *(const float4*)&lsum_lds[(ch << 6) + 16 * nf + 4 * quad];
          unsigned e01, e23;
          if (i < 4) { e01 = Ereg[i][2 * nf]; e23 = Ereg[i][2 * nf + 1]; }
          else       { e01 = eextra[wroff[2 * nf]]; e23 = eextra[wroff[2 * nf + 1]]; }
          float p0 = __uint_as_float(e01 << 16) * rl4.x;
          float p1 = __uint_as_float(e01 & 0xffff0000u) * rl4.y;
          float p2 = __uint_as_float(e23 << 16) * rl4.z;
          float p3 = __uint_as_float(e23 & 0xffff0000u) * rl4.w;
          plds[w][wroff[2 * nf]]     = pack2(p0, p1);
          plds[w][wroff[2 * nf + 1]] = pack2(p2, p3);
        }
        const bf16x8 a0 = ldp(&plds[w][rd0]);   // typed u32: order preserved
        const bf16x8 a1 = ldp(&plds[w][rd1]);
        __builtin_amdgcn_s_setprio(1);
        #pragma unroll
        for (int nf = 0; nf < 4; ++nf) {        // D[t][h]: lane&15=h, t=4q+r
          acc[nf] = MFMA(a0, vf[2 * nf], acc[nf]);
          acc[nf] = MFMA(a1, vf[2 * nf + 1], acc[nf]);
        }
        __builtin_amdgcn_s_setprio(0);
        if (g + 1 < g1) loadV(chOf(g + 1));     // in flight under next unpack
      }
    }
    const int rb = stripB ? 16 : 0;
    if (w < 4) {
      #pragma unroll
      for (int nf = 0; nf < 4; ++nf)
        #pragma unroll
        for (int r = 0; r < 4; ++r)
          red[w][rb + quad * 4 + r][16 * nf + l15] = acc[nf][r];
    }
    __syncthreads();
    if (w >= 4) {
      #pragma unroll
      for (int nf = 0; nf < 4; ++nf)
        #pragma unroll
        for (int r = 0; r < 4; ++r)
          red[w - 4][rb + quad * 4 + r][16 * nf + l15] += acc[nf][r];
    }
    __syncthreads();
  };
  pvpass(false);                                // tile j rows -> red[][0:16]
  pvpass(true);                                 // tile 31-j rows -> red[][16:32]

  {
    const int row = tid >> 4, c4 = (tid & 15) * 4;  // 32 rows x 16 col-quads
    float4 s0 = *(const float4*)(&red[0][row][c4]);
    float4 s1 = *(const float4*)(&red[1][row][c4]);
    float4 s2 = *(const float4*)(&red[2][row][c4]);
    float4 s3 = *(const float4*)(&red[3][row][c4]);
    float4 t;
    t.x = (s0.x + s1.x) + (s2.x + s3.x);
    t.y = (s0.y + s1.y) + (s2.y + s3.y);
    t.z = (s0.z + s1.z) + (s2.z + s3.z);
    t.w = (s0.w + s1.w) + (s2.w + s3.w);
    const int trow = (row < 16) ? (tb0 + row) : (tb1 + row - 16);
    *(float4*)(&out[QKbase + (size_t)trow * Hn + c4]) = t;
  }
}

extern "C" void kernel_launch(void* const* d_in, const int* in_sizes, int n_in,
                              void* d_out, int out_size, void* d_ws, size_t ws_size,
                              hipStream_t stream) {
  const float* x  = (const float*)d_in[0];
  const float* Wq = (const float*)d_in[1];
  const float* Wk = (const float*)d_in[2];
  const float* Wv = (const float*)d_in[3];
  char* ws = (char*)d_ws;                          // needs ~6.6 MB
  short* qb   = (short*)(ws);                      // 2 MB (T,H) (q pre-scaled)
  short* kb   = (short*)(ws + 2097152);            // 2 MB (T,H)
  short* vT   = (short*)(ws + 4194304);            // 2 MB (H,T)
  short* WbT  = (short*)(ws + 6291456);            // 144 KB
  float* Lsum = (float*)(ws + 6438912);            // 64 KB dense column sums
  unsigned* bar = (unsigned*)(ws + 6504448);       // grid-barrier counter
  float* outp = (float*)d_out;

  hipLaunchKernelGGL(wconv_kernel, dim3(288), dim3(256), 0, stream, Wq, Wk, Wv, WbT, Lsum, bar);
  hipLaunchKernelGGL(proj_kernel, dim3(Bn * Tn / 16), dim3(256), 0, stream, x, WbT, qb, kb, vT);
  hipLaunchKernelGGL(attn_kernel, dim3(NBLK), dim3(512), 0, stream, qb, kb, vT, Lsum, bar, outp);
}

// Round 8
// 185.191 us; speedup vs baseline: 1.0219x; 1.0219x over previous
//
#include <hip/hip_runtime.h>
#include <hip/hip_bf16.h>
#include <math.h>

#define Bn 8
#define Tn 2048
#define Cn 384
#define Hn 64
#define SCALE2 0.07362241f            // 384^-0.5 * log2(e); pre-folded into Wq
#define NBLK 512                      // attn grid: 2 blocks/CU exactly

using bf16x8 = __attribute__((ext_vector_type(8))) short;  // 8 bf16 = 4 VGPRs
using f32x4  = __attribute__((ext_vector_type(4))) float;
using u32x4  = __attribute__((ext_vector_type(4))) unsigned;

#define MFMA(a, b, c) __builtin_amdgcn_mfma_f32_16x16x32_bf16((a), (b), (c), 0, 0, 0)

static __device__ __forceinline__ short f2bf(float f) {  // RNE fp32->bf16
  unsigned u = __float_as_uint(f);
  u += 0x7fffu + ((u >> 16) & 1u);
  return (short)(u >> 16);
}
static __device__ __forceinline__ float fexp2(float x) {  // v_exp_f32 (base-2)
#if __has_builtin(__builtin_amdgcn_exp2f)
  return __builtin_amdgcn_exp2f(x);
#else
  return exp2f(x);
#endif
}
static __device__ __forceinline__ float frcp(float x) {   // v_rcp_f32 (~1ulp)
#if __has_builtin(__builtin_amdgcn_rcpf)
  return __builtin_amdgcn_rcpf(x);
#else
  return 1.0f / x;
#endif
}
static __device__ __forceinline__ unsigned pack2(float lo, float hi) {
  return (unsigned)(unsigned short)f2bf(lo) | ((unsigned)(unsigned short)f2bf(hi) << 16);
}
// Typed (TBAA-safe) LDS 16B gather: 4 x u32 loads, compiler merges to b128.
static __device__ __forceinline__ bf16x8 ldp(const unsigned* p) {
  u32x4 t; t[0] = p[0]; t[1] = p[1]; t[2] = p[2]; t[3] = p[3];
  return __builtin_bit_cast(bf16x8, t);
}
// Software grid barrier (graph-capture-safe; co-residency by construction:
// VGPR<=128 (waves_per_eu(4,4)) + LDS 58KB -> exactly 2 blocks/CU x 256 = 512).
static __device__ __forceinline__ void grid_barrier(unsigned* cnt) {
  __syncthreads();
  if (threadIdx.x == 0) {
    __threadfence();                          // release my Lsum atomics
    atomicAdd(cnt, 1u);                       // device-scope arrive
    while (__hip_atomic_load(cnt, __ATOMIC_ACQUIRE, __HIP_MEMORY_SCOPE_AGENT)
           < (unsigned)NBLK)
      __builtin_amdgcn_s_sleep(8);
  }
  __syncthreads();
}

// ---------------- K0: W -> WbT (192x384) bf16 (Wq pre-scaled) + zero Lsum ---
__global__ __launch_bounds__(256) void wconv_kernel(
    const float* __restrict__ Wq, const float* __restrict__ Wk,
    const float* __restrict__ Wv, short* __restrict__ WbT,
    float* __restrict__ Lsum, unsigned* __restrict__ bar) {
  int idx = blockIdx.x * 256 + threadIdx.x;  // n*384 + k, 73728 total
  if (idx < Bn * Tn) Lsum[idx] = 0.f;        // 16384 floats, pre-attn
  if (idx == 0) *bar = 0u;                   // grid-barrier counter
  int n = idx / 384, k = idx - n * 384;
  const float* W = (n < 64) ? Wq : (n < 128) ? Wk : Wv;
  float wv = W[k * 64 + (n & 63)];
  if (n < 64) wv *= SCALE2;                  // fold score scale into q
  WbT[idx] = f2bf(wv);
}

// ---------------- K1: proj GEMM, 16-row tiles (1024 blocks, 4/CU) -----------
__global__ __launch_bounds__(256) void proj_kernel(
    const float* __restrict__ x, const short* __restrict__ WbT,
    short* __restrict__ qb, short* __restrict__ kb, short* __restrict__ vT) {
  __shared__ short xs[16][392];    // stride 392: banks 2-way (free)
  __shared__ short vtile[64][20];  // v-tile transpose bounce
  const int tid = threadIdx.x;
  const int t0 = blockIdx.x * 16;  // global row (b*2048 + t)
  const float* xb = x + (size_t)t0 * Cn;
  #pragma unroll
  for (int i = 0; i < 6; ++i) {
    int j = tid + i * 256;  // float4 index, 1536 total
    int row = j / 96, colv = (j - row * 96) * 4;
    float4 v = *(const float4*)(xb + row * Cn + colv);
    short4 s4; s4.x = f2bf(v.x); s4.y = f2bf(v.y); s4.z = f2bf(v.z); s4.w = f2bf(v.w);
    *(short4*)(&xs[row][colv]) = s4;
  }
  __syncthreads();
  const int w = tid >> 6, l15 = tid & 15, quad = (tid & 63) >> 4;
  f32x4 acc[3] = {};
  for (int ks = 0; ks < 12; ++ks) {
    bf16x8 a = *(const bf16x8*)(&xs[l15][ks * 32 + quad * 8]);
    #pragma unroll
    for (int cf = 0; cf < 3; ++cf) {
      bf16x8 bfr = *(const bf16x8*)(WbT + (size_t)(48 * w + 16 * cf + l15) * Cn + ks * 32 + quad * 8);
      acc[cf] = MFMA(a, bfr, acc[cf]);
    }
  }
  #pragma unroll
  for (int cf = 0; cf < 3; ++cf) {
    int cbase = 48 * w + 16 * cf, c = cbase + l15;
    #pragma unroll
    for (int r = 0; r < 4; ++r) {
      int row = t0 + quad * 4 + r;
      short val = f2bf(acc[cf][r]);
      if (cbase < 64)       qb[(size_t)row * Hn + c] = val;
      else if (cbase < 128) kb[(size_t)row * Hn + (c - 64)] = val;
      else                  vtile[c - 128][quad * 4 + r] = val;
    }
  }
  __syncthreads();
  const int b = t0 >> 11, t0l = t0 & 2047;
  int h = tid >> 2, tseg = (tid & 3) * 4;
  *(short4*)(vT + ((size_t)(b * Hn + h)) * Tn + t0l + tseg) =
      *(const short4*)(&vtile[h][tseg]);
}

// ---------------- K2: FUSED attn: QK^T+exp ONCE, E in registers -------------
// 512 blocks x 512 thr (8 waves). amdgpu_waves_per_eu(4,4): min AND MAX pinned
// -> allocator budget 128 VGPR. (r6 launch_bounds(512,4) and r7
// waves_per_eu(4) both only set the MIN -> compiler targeted 8 waves/EU,
// 64 VGPR, and rematerialized kf/vf/Ereg from L2 every use: 103us at
// MfmaUtil 1.6%. LDS 58KB caps occupancy at 2 blocks/CU = 4 waves/EU anyway,
// so (4,4) costs nothing and unlocks the registers.)
// Block = (b = bid&7, pair j, quarter): 16 rows of tile j + 16 rows of tile
// 31-j -> 33 chunk-items/block; waves 0-6 own 4 items, wave 7 owns 5.
// Items 0-3 keep packed E in Ereg[4][8] (32 VGPR); wave 7's 5th item goes to
// the eextra LDS buffer (wroff layout) instead of registers.
// Phase 1 per item: 8 MFMA S^T=K.Q' (D[s][t], lane&15=t), mask+exp2, pack,
//   column sums via width-16 shfl_xor butterfly -> LDS accumulate.
// Flush Lsum (coalesced atomics), software grid barrier, rcpL -> LDS.
// Phase 2 (two strip-passes): unpack E, *rcpL, repack, per-wave XOR-swizzled
//   LDS transpose (typed u32, no barriers), 8 PV MFMA vs vT; cross-wave
//   reduce via red[4][32][64]; coalesced float4 stores.
__global__ __launch_bounds__(512)
__attribute__((amdgpu_waves_per_eu(4, 4)))
void attn_kernel(
    const short* __restrict__ qb, const short* __restrict__ kb,
    const short* __restrict__ vT, float* __restrict__ Lsum,
    unsigned* __restrict__ bar, float* __restrict__ out) {
  __shared__ alignas(16) float lsum_lds[2048];   // col sums, then rcpL (8KB)
  __shared__ alignas(16) unsigned plds[8][512];  // per-wave 2KB P tile (16KB)
  __shared__ alignas(16) float red[4][32][64];   // cross-wave reduce (32KB)
  __shared__ alignas(16) unsigned eextra[512];   // wave7 5th-item E (2KB)

  const int bid = blockIdx.x;
  const int b = bid & 7;                   // XCD-locked batch
  const int r_ = bid >> 3;                 // 0..63
  const int j = r_ >> 2;                   // pair 0..15
  const int quarter = r_ & 3;
  const int tA = j, tB = 31 - j;           // light tile, heavy tile
  const int tid = threadIdx.x;
  const int w = tid >> 6, l15 = tid & 15, quad = (tid & 63) >> 4;
  const int lo = (w * 33) >> 3, hi = ((w + 1) * 33) >> 3;  // 4 (w<7) or 5 (w=7)
  const int tb0 = (tA << 6) + (quarter << 4);
  const int tb1 = (tB << 6) + (quarter << 4);
  const size_t QKbase = (size_t)b * Tn * Hn;
  const size_t Vbase  = (size_t)b * Hn * Tn;

  for (int s = tid; s < 2048; s += 512) lsum_lds[s] = 0.f;
  __syncthreads();

  // XOR swizzle: byte ^= (l15&7)<<4 breaks the 128B-row same-bank pattern.
  const int swz = (l15 & 7) << 4;
  int wroff[8];                            // u32 offsets: s = 16nf+4q+{2p,2p+1}
  #pragma unroll
  for (int nf = 0; nf < 4; ++nf)
    #pragma unroll
    for (int p = 0; p < 2; ++p)
      wroff[2 * nf + p] = (l15 * 128 + ((nf * 32 + quad * 8 + p * 4) ^ swz)) >> 2;
  const int rd0 = (l15 * 128 + ((quad * 16) ^ swz)) >> 2;        // s = 8q..8q+7
  const int rd1 = (l15 * 128 + ((64 + quad * 16) ^ swz)) >> 2;   // s = 32+8q..+7

  auto chOf = [&](int g) { return (g > tA) ? (g - tA - 1) : g; };

  bf16x8 kf[8], vf[8];
  auto loadK = [&](int ch) {               // A[m=s][k=h] frags for S^T
    const int s0 = ch << 6;
    #pragma unroll
    for (int nf = 0; nf < 4; ++nf) {
      const size_t kr = QKbase + (size_t)(s0 + 16 * nf + l15) * Hn;
      kf[2 * nf]     = *(const bf16x8*)(kb + kr + quad * 8);
      kf[2 * nf + 1] = *(const bf16x8*)(kb + kr + 32 + quad * 8);
    }
  };
  auto loadV = [&](int ch) {               // B[n=h][k=s] frags for PV
    const int s0 = ch << 6;
    #pragma unroll
    for (int nf = 0; nf < 4; ++nf) {
      const size_t vr = Vbase + (size_t)(16 * nf + l15) * Tn + s0;
      vf[2 * nf]     = *(const bf16x8*)(vT + vr + quad * 8);
      vf[2 * nf + 1] = *(const bf16x8*)(vT + vr + 32 + quad * 8);
    }
  };

  // ---------------- phase 1: scores + exp + col-sums, E kept in regs --------
  unsigned Ereg[4][8];                     // statically indexed (unrolled i)
  loadK(chOf(lo));
  #pragma unroll
  for (int i = 0; i < 5; ++i) {
    const int g = lo + i;
    if (g < hi) {
      const int ch = chOf(g);
      const int tbase = (g > tA) ? tb1 : tb0;
      const bool diag = (ch == ((g > tA) ? tB : tA));
      const size_t qrow = QKbase + (size_t)(tbase + l15) * Hn;
      const bf16x8 qf0 = *(const bf16x8*)(qb + qrow + quad * 8);
      const bf16x8 qf1 = *(const bf16x8*)(qb + qrow + 32 + quad * 8);
      f32x4 sc[4] = {};                    // D[s][t]: lane&15 = t
      __builtin_amdgcn_s_setprio(1);
      #pragma unroll
      for (int nf = 0; nf < 4; ++nf) {
        sc[nf] = MFMA(kf[2 * nf], qf0, sc[nf]);
        sc[nf] = MFMA(kf[2 * nf + 1], qf1, sc[nf]);
      }
      __builtin_amdgcn_s_setprio(0);
      if (g + 1 < hi) loadK(chOf(g + 1));  // in flight under exp/butterfly
      const int tg = tbase + l15;
      #pragma unroll
      for (int nf = 0; nf < 4; ++nf) {
        f32x4 ev;
        if (diag) {
          #pragma unroll
          for (int r = 0; r < 4; ++r) {
            const int s = (ch << 6) + 16 * nf + 4 * quad + r;
            ev[r] = fexp2((tg < s) ? -INFINITY : sc[nf][r]);
          }
        } else {
          #pragma unroll
          for (int r = 0; r < 4; ++r) ev[r] = fexp2(sc[nf][r]);
        }
        if (i < 4) {
          Ereg[i][2 * nf]     = pack2(ev[0], ev[1]);
          Ereg[i][2 * nf + 1] = pack2(ev[2], ev[3]);
        } else {                           // only wave 7 reaches i==4
          eextra[wroff[2 * nf]]     = pack2(ev[0], ev[1]);
          eextra[wroff[2 * nf + 1]] = pack2(ev[2], ev[3]);
        }
        #pragma unroll
        for (int m = 1; m < 16; m <<= 1)   // sum over t (lane&15) per column
          #pragma unroll
          for (int r = 0; r < 4; ++r)
            ev[r] += __shfl_xor(ev[r], m, 16);
        if (l15 == 0) {
          #pragma unroll
          for (int r = 0; r < 4; ++r)
            atomicAdd(&lsum_lds[(ch << 6) + 16 * nf + 4 * quad + r], ev[r]);
        }
      }
    }
  }
  __syncthreads();
  for (int s = tid; s < 2048; s += 512)
    atomicAdd(&Lsum[b * Tn + s], lsum_lds[s]);   // coalesced flush
  grid_barrier(bar);
  for (int s = tid; s < 2048; s += 512)          // agent-scope load: coherent
    lsum_lds[s] = frcp(__hip_atomic_load(&Lsum[b * Tn + s],
                                         __ATOMIC_RELAXED,
                                         __HIP_MEMORY_SCOPE_AGENT));
  __syncthreads();

  // ---------------- phase 2: P = E*rcpL, transpose, PV, reduce, store -------
  f32x4 acc[4];
  auto pvpass = [&](bool stripB) {
    #pragma unroll
    for (int nf = 0; nf < 4; ++nf) acc[nf] = f32x4{0.f, 0.f, 0.f, 0.f};
    const int g0 = stripB ? ((lo > tA + 1) ? lo : tA + 1) : lo;
    const int g1 = stripB ? hi : ((hi < tA + 1) ? hi : tA + 1);
    if (g0 < g1) loadV(chOf(g0));
    #pragma unroll
    for (int i = 0; i < 5; ++i) {
      const int g = lo + i;
      if (g >= g0 && g < g1) {
        const int ch = chOf(g);
        #pragma unroll
        for (int nf = 0; nf < 4; ++nf) {
          float4 rl4 = *(const float4*)&lsum_lds[(ch << 6) + 16 * nf + 4 * quad];
          unsigned e01, e23;
          if (i < 4) { e01 = Ereg[i][2 * nf]; e23 = Ereg[i][2 * nf + 1]; }
          else       { e01 = eextra[wroff[2 * nf]]; e23 = eextra[wroff[2 * nf + 1]]; }
          float p0 = __uint_as_float(e01 << 16) * rl4.x;
          float p1 = __uint_as_float(e01 & 0xffff0000u) * rl4.y;
          float p2 = __uint_as_float(e23 << 16) * rl4.z;
          float p3 = __uint_as_float(e23 & 0xffff0000u) * rl4.w;
          plds[w][wroff[2 * nf]]     = pack2(p0, p1);
          plds[w][wroff[2 * nf + 1]] = pack2(p2, p3);
        }
        const bf16x8 a0 = ldp(&plds[w][rd0]);   // typed u32: order preserved
        const bf16x8 a1 = ldp(&plds[w][rd1]);
        __builtin_amdgcn_s_setprio(1);
        #pragma unroll
        for (int nf = 0; nf < 4; ++nf) {        // D[t][h]: lane&15=h, t=4q+r
          acc[nf] = MFMA(a0, vf[2 * nf], acc[nf]);
          acc[nf] = MFMA(a1, vf[2 * nf + 1], acc[nf]);
        }
        __builtin_amdgcn_s_setprio(0);
        if (g + 1 < g1) loadV(chOf(g + 1));     // in flight under next unpack
      }
    }
    const int rb = stripB ? 16 : 0;
    if (w < 4) {
      #pragma unroll
      for (int nf = 0; nf < 4; ++nf)
        #pragma unroll
        for (int r = 0; r < 4; ++r)
          red[w][rb + quad * 4 + r][16 * nf + l15] = acc[nf][r];
    }
    __syncthreads();
    if (w >= 4) {
      #pragma unroll
      for (int nf = 0; nf < 4; ++nf)
        #pragma unroll
        for (int r = 0; r < 4; ++r)
          red[w - 4][rb + quad * 4 + r][16 * nf + l15] += acc[nf][r];
    }
    __syncthreads();
  };
  pvpass(false);                                // tile j rows -> red[][0:16]
  pvpass(true);                                 // tile 31-j rows -> red[][16:32]

  {
    const int row = tid >> 4, c4 = (tid & 15) * 4;  // 32 rows x 16 col-quads
    float4 s0 = *(const float4*)(&red[0][row][c4]);
    float4 s1 = *(const float4*)(&red[1][row][c4]);
    float4 s2 = *(const float4*)(&red[2][row][c4]);
    float4 s3 = *(const float4*)(&red[3][row][c4]);
    float4 t;
    t.x = (s0.x + s1.x) + (s2.x + s3.x);
    t.y = (s0.y + s1.y) + (s2.y + s3.y);
    t.z = (s0.z + s1.z) + (s2.z + s3.z);
    t.w = (s0.w + s1.w) + (s2.w + s3.w);
    const int trow = (row < 16) ? (tb0 + row) : (tb1 + row - 16);
    *(float4*)(&out[QKbase + (size_t)trow * Hn + c4]) = t;
  }
}

extern "C" void kernel_launch(void* const* d_in, const int* in_sizes, int n_in,
                              void* d_out, int out_size, void* d_ws, size_t ws_size,
                              hipStream_t stream) {
  const float* x  = (const float*)d_in[0];
  const float* Wq = (const float*)d_in[1];
  const float* Wk = (const float*)d_in[2];
  const float* Wv = (const float*)d_in[3];
  char* ws = (char*)d_ws;                          // needs ~6.6 MB
  short* qb   = (short*)(ws);                      // 2 MB (T,H) (q pre-scaled)
  short* kb   = (short*)(ws + 2097152);            // 2 MB (T,H)
  short* vT   = (short*)(ws + 4194304);            // 2 MB (H,T)
  short* WbT  = (short*)(ws + 6291456);            // 144 KB
  float* Lsum = (float*)(ws + 6438912);            // 64 KB dense column sums
  unsigned* bar = (unsigned*)(ws + 6504448);       // grid-barrier counter
  float* outp = (float*)d_out;

  hipLaunchKernelGGL(wconv_kernel, dim3(288), dim3(256), 0, stream, Wq, Wk, Wv, WbT, Lsum, bar);
  hipLaunchKernelGGL(proj_kernel, dim3(Bn * Tn / 16), dim3(256), 0, stream, x, WbT, qb, kb, vT);
  hipLaunchKernelGGL(attn_kernel, dim3(NBLK), dim3(512), 0, stream, qb, kb, vT, Lsum, bar, outp);
}